// Round 7
// baseline (234.506 us; speedup 1.0000x reference)
//
#include <hip/hip_runtime.h>
#include <stdint.h>

// Workspace layout (~48.6 MB):
//   xh    @ 0      : [4096][1024] bf16 (8 MB)  x hi part (= K hi)
//   xl    @ 8 MB   : [4096][1024] bf16 (8 MB)  x lo part
//   Wh    @ 16 MB  : [2048][1024] bf16 (4 MB)  W_qv^T hi
//   Wl    @ 20 MB  : [2048][1024] bf16 (4 MB)  W_qv^T lo
//   qwsf  @ 24 MB  : [8][16][512][64] f32 (16 MB) q full f32
//   vt    @ 40 MB  : [8][16][64][512] bf16 (8 MB) v transposed per head
//   poshi @ 48 MB          : [1088][64] bf16
//   poslo @ 48 MB + 192 KB : [1088][64] bf16
//   posf  @ 48 MB + 384 KB : [512][64] f32 = sin/cos(k*f_j) for k=0..511
//
// BD trig factorization: BD[q,k] = Qw.pos[k-q+512] = Q~[q] . P~[k] where
// Q~ = [qs*cos(qf)+qc*sin(qf) | qc*cos(qf)-qs*sin(qf)] (f32 rotation, split),
// P~[k] = pos[k+512] (= [sin(kf)|cos(kf)], already hi/lo in poshi/poslo).
// So A2 accumulates into the SAME MFMA acc as QK^T: no band, no gather.

typedef __attribute__((ext_vector_type(8))) short s8v;
typedef __attribute__((ext_vector_type(4))) float f4v;

#define MFMA_BF16 __builtin_amdgcn_mfma_f32_16x16x32_bf16

__device__ __forceinline__ float bf2f(unsigned short s) {
  unsigned int u = ((unsigned int)s) << 16;
  float f;
  __builtin_memcpy(&f, &u, 4);
  return f;
}
__device__ __forceinline__ unsigned short f2bf(float f) {
  unsigned int u;
  __builtin_memcpy(&u, &f, 4);
  unsigned int r = (u + 0x7fffu + ((u >> 16) & 1u)) >> 16;
  return (unsigned short)r;
}
__device__ __forceinline__ bool is_bf16_in(const void* mask) {
  return (((const unsigned int*)mask)[0] & 0xFFFFu) != 0u;
}
__device__ __forceinline__ void gload16(const void* g, void* l) {
  __builtin_amdgcn_global_load_lds((const __attribute__((address_space(1))) void*)g,
                                   (__attribute__((address_space(3))) void*)l, 16, 0, 0);
}

// ---------------- split x -> xh, xl (bf16 hi/lo) ----------------
__global__ __launch_bounds__(256) void k_split_x(const void* __restrict__ X,
                                                 const void* __restrict__ mask,
                                                 unsigned short* __restrict__ xh,
                                                 unsigned short* __restrict__ xl) {
  const bool isb = is_bf16_in(mask);
  const int i = (blockIdx.x * 256 + threadIdx.x) * 8;
  s8v oh, ol;
  if (isb) {
    oh = *(const s8v*)((const unsigned short*)X + i);
#pragma unroll
    for (int j = 0; j < 8; ++j) ol[j] = 0;
  } else {
    const float* xf = (const float*)X + i;
#pragma unroll
    for (int j = 0; j < 8; ++j) {
      float v = xf[j];
      unsigned short hi = f2bf(v);
      oh[j] = (short)hi;
      ol[j] = (short)f2bf(v - bf2f(hi));
    }
  }
  *(s8v*)(xh + i) = oh;
  *(s8v*)(xl + i) = ol;
}

// ------- W transpose+split: W[1024][2048] -> Wh/Wl[2048][1024] bf16 -------
__global__ __launch_bounds__(256) void k_transpose(const void* __restrict__ W,
                                                   const void* __restrict__ mask,
                                                   unsigned short* __restrict__ Wh,
                                                   unsigned short* __restrict__ Wl) {
  __shared__ unsigned short th[64][65];
  __shared__ unsigned short tl[64][65];
  const bool isb = is_bf16_in(mask);
  const int n0 = blockIdx.x * 64;
  const int k0 = blockIdx.y * 64;
  const int t = threadIdx.x;
#pragma unroll
  for (int i = 0; i < 16; ++i) {
    int idx = t + i * 256;
    int kl = idx >> 6, nl = idx & 63;
    int src = (k0 + kl) * 2048 + n0 + nl;
    unsigned short hi, lo;
    if (isb) {
      hi = ((const unsigned short*)W)[src];
      lo = 0;
    } else {
      float v = ((const float*)W)[src];
      hi = f2bf(v);
      lo = f2bf(v - bf2f(hi));
    }
    th[nl][kl] = hi;
    tl[nl][kl] = lo;
  }
  __syncthreads();
#pragma unroll
  for (int i = 0; i < 16; ++i) {
    int idx = t + i * 256;
    int nl = idx >> 6, kl = idx & 63;
    Wh[(n0 + nl) * 1024 + k0 + kl] = th[nl][kl];
    Wl[(n0 + nl) * 1024 + k0 + kl] = tl[nl][kl];
  }
}

// ---- pos tables: hi/lo split bf16 [1088][64] + f32 posf[512][64] ----
__global__ __launch_bounds__(256) void k_pos(unsigned short* __restrict__ poshi,
                                             unsigned short* __restrict__ poslo,
                                             float* __restrict__ posf) {
  int idx = blockIdx.x * 256 + threadIdx.x;
  if (idx >= 1088 * 64) return;
  int l = idx >> 6, i = idx & 63;
  unsigned short hi = 0, lo = 0;
  if (l < 1024) {
    int j = i & 31;
    float f = expf(-0.2971077539347156f * (float)j);  // -ln(10000)/31
    float ang = (float)(l - 512) * f;
    float v = (i < 32) ? sinf(ang) : cosf(ang);
    hi = f2bf(v);
    lo = f2bf(v - bf2f(hi));
    if (l >= 512) posf[(l - 512) * 64 + i] = v;  // sin/cos(k*f), k = l-512
  }
  poshi[idx] = hi;
  poslo[idx] = lo;
}

// ---- qv GEMM (global_load_lds staging): blocks x<8 -> q (split, f32 out),
//      x>=8 -> v (1 MFMA, bf16 out) ----
__global__ __launch_bounds__(256, 3) void k_gemm(const unsigned short* __restrict__ xh,
                                                 const unsigned short* __restrict__ xl,
                                                 const unsigned short* __restrict__ Wh,
                                                 const unsigned short* __restrict__ Wl,
                                                 float* __restrict__ qwsf,
                                                 unsigned short* __restrict__ vt) {
  __shared__ unsigned short Ah[128 * 32];
  __shared__ unsigned short Bh[128 * 32];
  __shared__ unsigned short Al2[128 * 32];
  __shared__ unsigned short Bl2[128 * 32];
  const int m0 = blockIdx.y * 128;
  const int n0 = blockIdx.x * 128;
  const bool isq = (n0 < 1024);
  const int t = threadIdx.x;
  const int w = t >> 6, lane = t & 63;
  const int wr = w >> 1, wc = w & 1;
  const int l16 = lane & 15, g = lane >> 4;
  const int ch0 = w * 128;  // wave-uniform chunk base (2 instrs x 64 lanes)

  f4v acc[4][4];
#pragma unroll
  for (int i = 0; i < 4; ++i)
#pragma unroll
    for (int j = 0; j < 4; ++j) acc[i][j] = (f4v){0.f, 0.f, 0.f, 0.f};

  for (int k0 = 0; k0 < 1024; k0 += 32) {
    __syncthreads();  // readers of previous tile done
#pragma unroll
    for (int i = 0; i < 2; ++i) {
      const int ch = ch0 + i * 64 + lane;
      const int r = ch >> 2, c = (ch & 3) * 8;
      const int ldsoff = (ch0 + i * 64) * 8;  // wave-uniform dest
      gload16(&xh[(m0 + r) * 1024 + k0 + c], &Ah[ldsoff]);
      gload16(&Wh[(n0 + r) * 1024 + k0 + c], &Bh[ldsoff]);
      if (isq) {
        gload16(&xl[(m0 + r) * 1024 + k0 + c], &Al2[ldsoff]);
        gload16(&Wl[(n0 + r) * 1024 + k0 + c], &Bl2[ldsoff]);
      }
    }
    __syncthreads();  // implicit vmcnt(0) drain
    s8v afh[4], bfh[4];
#pragma unroll
    for (int i = 0; i < 4; ++i) afh[i] = *(const s8v*)&Ah[(wr * 64 + i * 16 + l16) * 32 + g * 8];
#pragma unroll
    for (int j = 0; j < 4; ++j) bfh[j] = *(const s8v*)&Bh[(wc * 64 + j * 16 + l16) * 32 + g * 8];
    if (isq) {
      s8v afl[4], bfl[4];
#pragma unroll
      for (int i = 0; i < 4; ++i) afl[i] = *(const s8v*)&Al2[(wr * 64 + i * 16 + l16) * 32 + g * 8];
#pragma unroll
      for (int j = 0; j < 4; ++j) bfl[j] = *(const s8v*)&Bl2[(wc * 64 + j * 16 + l16) * 32 + g * 8];
#pragma unroll
      for (int i = 0; i < 4; ++i)
#pragma unroll
        for (int j = 0; j < 4; ++j) {
          acc[i][j] = MFMA_BF16(afh[i], bfh[j], acc[i][j], 0, 0, 0);
          acc[i][j] = MFMA_BF16(afl[i], bfh[j], acc[i][j], 0, 0, 0);
          acc[i][j] = MFMA_BF16(afh[i], bfl[j], acc[i][j], 0, 0, 0);
        }
    } else {
#pragma unroll
      for (int i = 0; i < 4; ++i)
#pragma unroll
        for (int j = 0; j < 4; ++j) acc[i][j] = MFMA_BF16(afh[i], bfh[j], acc[i][j], 0, 0, 0);
    }
  }

#pragma unroll
  for (int i = 0; i < 4; ++i) {
#pragma unroll
    for (int j = 0; j < 4; ++j) {
      int col = n0 + wc * 64 + j * 16 + l16;
#pragma unroll
      for (int jj = 0; jj < 4; ++jj) {
        int row = m0 + wr * 64 + i * 16 + g * 4 + jj;
        int bb = row >> 9, l = row & 511;
        if (isq) {
          int hh = col >> 6, d = col & 63;
          qwsf[((bb * 16 + hh) * 512 + l) * 64 + d] = acc[i][j][jj];
        } else {
          int c2 = col - 1024;
          int hh = c2 >> 6, d = c2 & 63;
          vt[((bb * 16 + hh) * 64 + d) * 512 + l] = f2bf(acc[i][j][jj]);
        }
      }
    }
  }
}

// ---------------- fused relative attention v4 (trig-GEMM band) ----------------
// block (qt, bh), 256 thr; wave w owns q-rows [q0+16w, q0+16w+16).
// XOR-swizzled [64][64] LDS tiles: elem block e8' = e8 ^ (row&7).
__global__ __launch_bounds__(256, 3) void k_attn(const unsigned short* __restrict__ xh,
                                                 const unsigned short* __restrict__ xl,
                                                 const float* __restrict__ qwsf,
                                                 const unsigned short* __restrict__ vt,
                                                 const unsigned short* __restrict__ poshi,
                                                 const unsigned short* __restrict__ poslo,
                                                 const float* __restrict__ posf,
                                                 const void* __restrict__ rrb,
                                                 const void* __restrict__ rwb,
                                                 const void* __restrict__ mask,
                                                 void* __restrict__ out) {
  __shared__ unsigned short Kh[64 * 64];
  __shared__ unsigned short Kl[64 * 64];
  __shared__ unsigned short Vv[64 * 64];
  __shared__ unsigned short Th[64 * 64];  // P~ hi (pos rows 512+k)
  __shared__ unsigned short Tl[64 * 64];  // P~ lo
  __shared__ unsigned short P[4][16][68];

  const bool isb = is_bf16_in(mask);
  const int qt = blockIdx.x;
  const int bh = blockIdx.y;
  const int b = bh >> 4, h = bh & 15;
  const int q0 = qt << 6;
  const int t = threadIdx.x;
  const int w = t >> 6;
  const int lane = t & 63;
  const int l16 = lane & 15;
  const int g = lane >> 4;
  const int bh64 = (b * 16 + h) * 64;

  // staging geometry: row = (t>>3) + 32i, elem block e8 = t&7, swizzled
  const int srow = t >> 3;
  const int swz = ((t & 7) ^ (srow & 7)) << 3;  // swizzled elem offset (write)

  // ---- prologue: stage k-tile 0 ----
#pragma unroll
  for (int i = 0; i < 2; ++i) {
    int row = srow + i * 32;
    int scc = (t & 7) * 8;
    *(s8v*)&Kh[row * 64 + swz] = *(const s8v*)&xh[(b * 512 + row) * 1024 + h * 64 + scc];
    *(s8v*)&Kl[row * 64 + swz] = *(const s8v*)&xl[(b * 512 + row) * 1024 + h * 64 + scc];
    *(s8v*)&Vv[row * 64 + swz] = *(const s8v*)&vt[(bh64 + row) * 512 + scc];
    *(s8v*)&Th[row * 64 + swz] = *(const s8v*)&poshi[(512 + row) * 64 + scc];
    *(s8v*)&Tl[row * 64 + swz] = *(const s8v*)&poslo[(512 + row) * 64 + scc];
  }

  // ---- Q prep: split (q+rrb); rotate (q+rwb) by sin/cos(q*f) and split ----
  s8v qrh[2], qrl[2], qth[2], qtl[2];
  {
    const int qrow = q0 + (w << 4) + l16;
    const float* qb = &qwsf[((b * 16 + h) * 512 + qrow) * 64];
    float qw2[2][8];
#pragma unroll
    for (int f = 0; f < 2; ++f) {
      int d0 = f * 32 + g * 8;
#pragma unroll
      for (int j = 0; j < 8; ++j) {
        float qf = qb[d0 + j];
        float b1 = isb ? bf2f(((const unsigned short*)rrb)[h * 64 + d0 + j])
                       : ((const float*)rrb)[h * 64 + d0 + j];
        float b2 = isb ? bf2f(((const unsigned short*)rwb)[h * 64 + d0 + j])
                       : ((const float*)rwb)[h * 64 + d0 + j];
        float s1 = qf + b1;
        unsigned short h1 = f2bf(s1);
        qrh[f][j] = (short)h1;
        qrl[f][j] = (short)f2bf(s1 - bf2f(h1));
        qw2[f][j] = qf + b2;
      }
    }
#pragma unroll
    for (int j = 0; j < 8; ++j) {
      int jd = g * 8 + j;
      float s = posf[qrow * 64 + jd];       // sin(q*f_j)
      float c = posf[qrow * 64 + 32 + jd];  // cos(q*f_j)
      float qs = qw2[0][j], qc = qw2[1][j];
      float Qp = qs * c + qc * s;   // pairs with sin(k*f)
      float Qpp = qc * c - qs * s;  // pairs with cos(k*f)
      unsigned short h0 = f2bf(Qp);
      qth[0][j] = (short)h0;
      qtl[0][j] = (short)f2bf(Qp - bf2f(h0));
      unsigned short h1 = f2bf(Qpp);
      qth[1][j] = (short)h1;
      qtl[1][j] = (short)f2bf(Qpp - bf2f(h1));
    }
  }

  f4v accO[4];
#pragma unroll
  for (int d = 0; d < 4; ++d) accO[d] = (f4v){0.f, 0.f, 0.f, 0.f};
  float mrun[4] = {-3.0e38f, -3.0e38f, -3.0e38f, -3.0e38f};
  float lrun[4] = {0.f, 0.f, 0.f, 0.f};

  __syncthreads();

#pragma unroll 1
  for (int kt = 0; kt < 8; ++kt) {
    const int k0 = kt << 6;

    // ---- T14: issue next tile's loads early (regs), write after barrier ----
    s8v nKh[2], nKl[2], nV[2], nTh[2], nTl[2];
    const bool hasNext = (kt < 7);
    if (hasNext) {
      const int k0n = k0 + 64;
      const int scc = (t & 7) * 8;
#pragma unroll
      for (int i = 0; i < 2; ++i) {
        int row = srow + i * 32;
        nKh[i] = *(const s8v*)&xh[(b * 512 + k0n + row) * 1024 + h * 64 + scc];
        nKl[i] = *(const s8v*)&xl[(b * 512 + k0n + row) * 1024 + h * 64 + scc];
        nV[i] = *(const s8v*)&vt[(bh64 + row) * 512 + k0n + scc];
        nTh[i] = *(const s8v*)&poshi[(512 + k0n + row) * 64 + scc];
        nTl[i] = *(const s8v*)&poslo[(512 + k0n + row) * 64 + scc];
      }
    }

    // ---- logits: (Qr.K^T + Q~.P~^T) into one accumulator ----
    f4v acc[4];
#pragma unroll
    for (int ct = 0; ct < 4; ++ct) acc[ct] = (f4v){0.f, 0.f, 0.f, 0.f};
#pragma unroll
    for (int f = 0; f < 2; ++f) {
#pragma unroll
      for (int ct = 0; ct < 4; ++ct) {
        const int kr = ct * 16 + l16;
        const int eo = (((4 * f + g) ^ (l16 & 7)) << 3);  // swizzled read
        s8v kh = *(const s8v*)&Kh[kr * 64 + eo];
        s8v klo = *(const s8v*)&Kl[kr * 64 + eo];
        s8v ph = *(const s8v*)&Th[kr * 64 + eo];
        s8v pl = *(const s8v*)&Tl[kr * 64 + eo];
        acc[ct] = MFMA_BF16(qrh[f], kh, acc[ct], 0, 0, 0);
        acc[ct] = MFMA_BF16(qrl[f], kh, acc[ct], 0, 0, 0);
        acc[ct] = MFMA_BF16(qrh[f], klo, acc[ct], 0, 0, 0);
        acc[ct] = MFMA_BF16(qth[f], ph, acc[ct], 0, 0, 0);
        acc[ct] = MFMA_BF16(qtl[f], ph, acc[ct], 0, 0, 0);
        acc[ct] = MFMA_BF16(qth[f], pl, acc[ct], 0, 0, 0);
      }
    }

    // mask + -inf
    float sv[4][4];
#pragma unroll
    for (int ct = 0; ct < 4; ++ct) {
      int mi = b * 512 + k0 + ct * 16 + l16;
      float mv = isb ? bf2f(((const unsigned short*)mask)[mi]) : ((const float*)mask)[mi];
#pragma unroll
      for (int jj = 0; jj < 4; ++jj) {
        float s = acc[ct][jj] * mv;
        if (s == 0.f) s = -__builtin_inff();
        sv[ct][jj] = s;
      }
    }

    // in-register online softmax (rows 4g+jj live in 16-lane groups)
    float sc[4];
#pragma unroll
    for (int jj = 0; jj < 4; ++jj) {
      float pm = fmaxf(fmaxf(sv[0][jj], sv[1][jj]), fmaxf(sv[2][jj], sv[3][jj]));
      pm = fmaxf(pm, __shfl_xor(pm, 1));
      pm = fmaxf(pm, __shfl_xor(pm, 2));
      pm = fmaxf(pm, __shfl_xor(pm, 4));
      pm = fmaxf(pm, __shfl_xor(pm, 8));
      float mnew = fmaxf(mrun[jj], pm);
      float scale = __expf(mrun[jj] - mnew);
      float ps = 0.f;
#pragma unroll
      for (int ct = 0; ct < 4; ++ct) {
        float p = __expf(sv[ct][jj] - mnew);
        unsigned short pb = f2bf(p);
        P[w][4 * g + jj][ct * 16 + l16] = pb;
        ps += bf2f(pb);
      }
      ps += __shfl_xor(ps, 1);
      ps += __shfl_xor(ps, 2);
      ps += __shfl_xor(ps, 4);
      ps += __shfl_xor(ps, 8);
      lrun[jj] = lrun[jj] * scale + ps;
      mrun[jj] = mnew;
      sc[jj] = scale;
    }

    // O rescale + PV MFMA (V from swizzled LDS)
#pragma unroll
    for (int d = 0; d < 4; ++d)
#pragma unroll
      for (int jj = 0; jj < 4; ++jj) accO[d][jj] *= sc[jj];
#pragma unroll
    for (int ks = 0; ks < 2; ++ks) {
      s8v pf = *(const s8v*)&P[w][l16][ks * 32 + g * 8];
#pragma unroll
      for (int d = 0; d < 4; ++d) {
        const int vr = d * 16 + l16;
        const int eo = (((4 * ks + g) ^ (l16 & 7)) << 3);
        s8v vf = *(const s8v*)&Vv[vr * 64 + eo];
        accO[d] = MFMA_BF16(pf, vf, accO[d], 0, 0, 0);
      }
    }

    __syncthreads();  // all waves done reading this tile
    if (hasNext) {
#pragma unroll
      for (int i = 0; i < 2; ++i) {
        int row = srow + i * 32;
        *(s8v*)&Kh[row * 64 + swz] = nKh[i];
        *(s8v*)&Kl[row * 64 + swz] = nKl[i];
        *(s8v*)&Vv[row * 64 + swz] = nV[i];
        *(s8v*)&Th[row * 64 + swz] = nTh[i];
        *(s8v*)&Tl[row * 64 + swz] = nTl[i];
      }
    }
    __syncthreads();
  }

  float inv[4];
#pragma unroll
  for (int jj = 0; jj < 4; ++jj) inv[jj] = 1.0f / lrun[jj];
#pragma unroll
  for (int d = 0; d < 4; ++d) {
#pragma unroll
    for (int jj = 0; jj < 4; ++jj) {
      int row = q0 + (w << 4) + 4 * g + jj;
      int idx = (b * 512 + row) * 1024 + h * 64 + d * 16 + l16;
      float val = accO[d][jj] * inv[jj];
      if (isb) ((unsigned short*)out)[idx] = f2bf(val);
      else ((float*)out)[idx] = val;
    }
  }
}

extern "C" void kernel_launch(void* const* d_in, const int* in_sizes, int n_in,
                              void* d_out, int out_size, void* d_ws, size_t ws_size,
                              hipStream_t stream) {
  (void)in_sizes; (void)n_in; (void)out_size; (void)ws_size;
  const void* x    = d_in[0];
  const void* mask = d_in[1];
  const void* wqv  = d_in[2];
  const void* rrb  = d_in[3];
  const void* rwb  = d_in[4];

  char* ws = (char*)d_ws;
  unsigned short* xh    = (unsigned short*)(ws);
  unsigned short* xl    = (unsigned short*)(ws + (8u << 20));
  unsigned short* Wh    = (unsigned short*)(ws + (16u << 20));
  unsigned short* Wl    = (unsigned short*)(ws + (20u << 20));
  float*          qwsf  = (float*)(ws + (24u << 20));
  unsigned short* vt    = (unsigned short*)(ws + (40u << 20));
  unsigned short* poshi = (unsigned short*)(ws + (48u << 20));
  unsigned short* poslo = (unsigned short*)(ws + (48u << 20) + (192u << 10));
  float*          posf  = (float*)(ws + (48u << 20) + (384u << 10));

  k_pos<<<dim3(272), 256, 0, stream>>>(poshi, poslo, posf);
  k_transpose<<<dim3(32, 16), 256, 0, stream>>>(wqv, mask, Wh, Wl);
  k_split_x<<<dim3(2048), 256, 0, stream>>>(x, mask, xh, xl);
  k_gemm<<<dim3(16, 32), 256, 0, stream>>>(xh, xl, Wh, Wl, qwsf, vt);
  k_attn<<<dim3(8, 128), 256, 0, stream>>>(xh, xl, qwsf, vt, poshi, poslo, posf, rrb, rwb, mask, (void*)d_out);
}

// Round 8
// 202.704 us; speedup vs baseline: 1.1569x; 1.1569x over previous
//
#include <hip/hip_runtime.h>
#include <stdint.h>

// Workspace layout (~48.6 MB):
//   xh    @ 0      : [4096][1024] bf16 (8 MB)  x hi part (= K hi)
//   xl    @ 8 MB   : [4096][1024] bf16 (8 MB)  x lo part
//   Wh    @ 16 MB  : [2048][1024] bf16 (4 MB)  W_qv^T hi
//   Wl    @ 20 MB  : [2048][1024] bf16 (4 MB)  W_qv^T lo
//   qwsf  @ 24 MB  : [8][16][512][64] f32 (16 MB) q full f32
//   vt    @ 40 MB  : [8][16][64][512] bf16 (8 MB) v transposed per head
//   poshi @ 48 MB          : [1088][64] bf16
//   poslo @ 48 MB + 192 KB : [1088][64] bf16
//   posf  @ 48 MB + 384 KB : [512][64] f32 = sin/cos(k*f_j) for k=0..511
//
// k_gemm v2: T3-minimum 2-phase pipeline. Double-buffered LDS via
// global_load_lds; per iter: issue STAGE(t+1), compute tile t, vmcnt(0),
// raw s_barrier. Loads overlap ds_read+MFMA (round 7 exposed full latency:
// 7.2k cyc/step for 400 cyc of compute).
// k_attn: identical to round 7 except launch_bounds back to (256,2) —
// (256,3) caps VGPR at ~170 vs ~190 live -> spills suspected.

typedef __attribute__((ext_vector_type(8))) short s8v;
typedef __attribute__((ext_vector_type(4))) float f4v;

#define MFMA_BF16 __builtin_amdgcn_mfma_f32_16x16x32_bf16

__device__ __forceinline__ float bf2f(unsigned short s) {
  unsigned int u = ((unsigned int)s) << 16;
  float f;
  __builtin_memcpy(&f, &u, 4);
  return f;
}
__device__ __forceinline__ unsigned short f2bf(float f) {
  unsigned int u;
  __builtin_memcpy(&u, &f, 4);
  unsigned int r = (u + 0x7fffu + ((u >> 16) & 1u)) >> 16;
  return (unsigned short)r;
}
__device__ __forceinline__ bool is_bf16_in(const void* mask) {
  return (((const unsigned int*)mask)[0] & 0xFFFFu) != 0u;
}
__device__ __forceinline__ void gload16(const void* g, void* l) {
  __builtin_amdgcn_global_load_lds((const __attribute__((address_space(1))) void*)g,
                                   (__attribute__((address_space(3))) void*)l, 16, 0, 0);
}

// ---------------- split x -> xh, xl (bf16 hi/lo) ----------------
__global__ __launch_bounds__(256) void k_split_x(const void* __restrict__ X,
                                                 const void* __restrict__ mask,
                                                 unsigned short* __restrict__ xh,
                                                 unsigned short* __restrict__ xl) {
  const bool isb = is_bf16_in(mask);
  const int i = (blockIdx.x * 256 + threadIdx.x) * 8;
  s8v oh, ol;
  if (isb) {
    oh = *(const s8v*)((const unsigned short*)X + i);
#pragma unroll
    for (int j = 0; j < 8; ++j) ol[j] = 0;
  } else {
    const float* xf = (const float*)X + i;
#pragma unroll
    for (int j = 0; j < 8; ++j) {
      float v = xf[j];
      unsigned short hi = f2bf(v);
      oh[j] = (short)hi;
      ol[j] = (short)f2bf(v - bf2f(hi));
    }
  }
  *(s8v*)(xh + i) = oh;
  *(s8v*)(xl + i) = ol;
}

// ------- W transpose+split: W[1024][2048] -> Wh/Wl[2048][1024] bf16 -------
__global__ __launch_bounds__(256) void k_transpose(const void* __restrict__ W,
                                                   const void* __restrict__ mask,
                                                   unsigned short* __restrict__ Wh,
                                                   unsigned short* __restrict__ Wl) {
  __shared__ unsigned short th[64][65];
  __shared__ unsigned short tl[64][65];
  const bool isb = is_bf16_in(mask);
  const int n0 = blockIdx.x * 64;
  const int k0 = blockIdx.y * 64;
  const int t = threadIdx.x;
#pragma unroll
  for (int i = 0; i < 16; ++i) {
    int idx = t + i * 256;
    int kl = idx >> 6, nl = idx & 63;
    int src = (k0 + kl) * 2048 + n0 + nl;
    unsigned short hi, lo;
    if (isb) {
      hi = ((const unsigned short*)W)[src];
      lo = 0;
    } else {
      float v = ((const float*)W)[src];
      hi = f2bf(v);
      lo = f2bf(v - bf2f(hi));
    }
    th[nl][kl] = hi;
    tl[nl][kl] = lo;
  }
  __syncthreads();
#pragma unroll
  for (int i = 0; i < 16; ++i) {
    int idx = t + i * 256;
    int nl = idx >> 6, kl = idx & 63;
    Wh[(n0 + nl) * 1024 + k0 + kl] = th[nl][kl];
    Wl[(n0 + nl) * 1024 + k0 + kl] = tl[nl][kl];
  }
}

// ---- pos tables: hi/lo split bf16 [1088][64] + f32 posf[512][64] ----
__global__ __launch_bounds__(256) void k_pos(unsigned short* __restrict__ poshi,
                                             unsigned short* __restrict__ poslo,
                                             float* __restrict__ posf) {
  int idx = blockIdx.x * 256 + threadIdx.x;
  if (idx >= 1088 * 64) return;
  int l = idx >> 6, i = idx & 63;
  unsigned short hi = 0, lo = 0;
  if (l < 1024) {
    int j = i & 31;
    float f = expf(-0.2971077539347156f * (float)j);  // -ln(10000)/31
    float ang = (float)(l - 512) * f;
    float v = (i < 32) ? sinf(ang) : cosf(ang);
    hi = f2bf(v);
    lo = f2bf(v - bf2f(hi));
    if (l >= 512) posf[(l - 512) * 64 + i] = v;  // sin/cos(k*f), k = l-512
  }
  poshi[idx] = hi;
  poslo[idx] = lo;
}

// ---- qv GEMM v2 (2-phase counted pipeline): blocks x<8 -> q, x>=8 -> v ----
__global__ __launch_bounds__(256, 2) void k_gemm(const unsigned short* __restrict__ xh,
                                                 const unsigned short* __restrict__ xl,
                                                 const unsigned short* __restrict__ Wh,
                                                 const unsigned short* __restrict__ Wl,
                                                 float* __restrict__ qwsf,
                                                 unsigned short* __restrict__ vt) {
  // 2 buffers x 4 tiles x (128x32) bf16 = 64 KB. Tile order: Ah,Bh,Al,Bl.
  __shared__ unsigned short LDSS[2 * 16384];
  const int m0 = blockIdx.y * 128;
  const int n0 = blockIdx.x * 128;
  const bool isq = (n0 < 1024);
  const int t = threadIdx.x;
  const int w = t >> 6, lane = t & 63;
  const int wr = w >> 1, wc = w & 1;
  const int l16 = lane & 15, g = lane >> 4;
  const int ch0 = w * 128;  // wave-uniform chunk base

  // per-thread staging coords (2 chunks per tile)
  const int r0 = (ch0 + lane) >> 2, c0 = ((ch0 + lane) & 3) * 8;
  const int r1 = (ch0 + 64 + lane) >> 2, c1 = ((ch0 + 64 + lane) & 3) * 8;
  const int d0 = (ch0) * 8, d1 = (ch0 + 64) * 8;  // wave-uniform LDS elem offsets

  f4v acc[4][4];
#pragma unroll
  for (int i = 0; i < 4; ++i)
#pragma unroll
    for (int j = 0; j < 4; ++j) acc[i][j] = (f4v){0.f, 0.f, 0.f, 0.f};

  if (isq) {
    auto stage = [&](unsigned short* base, int k0) {
      gload16(&xh[(m0 + r0) * 1024 + k0 + c0], base + d0);
      gload16(&xh[(m0 + r1) * 1024 + k0 + c1], base + d1);
      gload16(&Wh[(n0 + r0) * 1024 + k0 + c0], base + 4096 + d0);
      gload16(&Wh[(n0 + r1) * 1024 + k0 + c1], base + 4096 + d1);
      gload16(&xl[(m0 + r0) * 1024 + k0 + c0], base + 8192 + d0);
      gload16(&xl[(m0 + r1) * 1024 + k0 + c1], base + 8192 + d1);
      gload16(&Wl[(n0 + r0) * 1024 + k0 + c0], base + 12288 + d0);
      gload16(&Wl[(n0 + r1) * 1024 + k0 + c1], base + 12288 + d1);
    };
    stage(LDSS, 0);
    asm volatile("s_waitcnt vmcnt(0)" ::: "memory");
    __builtin_amdgcn_s_barrier();
#pragma unroll 1
    for (int t32 = 0; t32 < 32; ++t32) {
      unsigned short* cur = LDSS + (t32 & 1) * 16384;
      if (t32 < 31) stage(LDSS + ((t32 + 1) & 1) * 16384, (t32 + 1) * 32);
      s8v afh[4], bfh[4], afl[4], bfl[4];
#pragma unroll
      for (int i = 0; i < 4; ++i) {
        const int ro = (wr * 64 + i * 16 + l16) * 32 + g * 8;
        afh[i] = *(const s8v*)&cur[ro];
        afl[i] = *(const s8v*)&cur[8192 + ro];
      }
#pragma unroll
      for (int j = 0; j < 4; ++j) {
        const int ro = (wc * 64 + j * 16 + l16) * 32 + g * 8;
        bfh[j] = *(const s8v*)&cur[4096 + ro];
        bfl[j] = *(const s8v*)&cur[12288 + ro];
      }
#pragma unroll
      for (int i = 0; i < 4; ++i)
#pragma unroll
        for (int j = 0; j < 4; ++j) {
          acc[i][j] = MFMA_BF16(afh[i], bfh[j], acc[i][j], 0, 0, 0);
          acc[i][j] = MFMA_BF16(afl[i], bfh[j], acc[i][j], 0, 0, 0);
          acc[i][j] = MFMA_BF16(afh[i], bfl[j], acc[i][j], 0, 0, 0);
        }
      if (t32 < 31) {
        asm volatile("s_waitcnt vmcnt(0)" ::: "memory");
        __builtin_amdgcn_s_barrier();
      }
    }
  } else {
    auto stage = [&](unsigned short* base, int k0) {
      gload16(&xh[(m0 + r0) * 1024 + k0 + c0], base + d0);
      gload16(&xh[(m0 + r1) * 1024 + k0 + c1], base + d1);
      gload16(&Wh[(n0 + r0) * 1024 + k0 + c0], base + 4096 + d0);
      gload16(&Wh[(n0 + r1) * 1024 + k0 + c1], base + 4096 + d1);
    };
    stage(LDSS, 0);
    asm volatile("s_waitcnt vmcnt(0)" ::: "memory");
    __builtin_amdgcn_s_barrier();
#pragma unroll 1
    for (int t32 = 0; t32 < 32; ++t32) {
      unsigned short* cur = LDSS + (t32 & 1) * 16384;
      if (t32 < 31) stage(LDSS + ((t32 + 1) & 1) * 16384, (t32 + 1) * 32);
      s8v afh[4], bfh[4];
#pragma unroll
      for (int i = 0; i < 4; ++i) afh[i] = *(const s8v*)&cur[(wr * 64 + i * 16 + l16) * 32 + g * 8];
#pragma unroll
      for (int j = 0; j < 4; ++j) bfh[j] = *(const s8v*)&cur[4096 + (wc * 64 + j * 16 + l16) * 32 + g * 8];
#pragma unroll
      for (int i = 0; i < 4; ++i)
#pragma unroll
        for (int j = 0; j < 4; ++j) acc[i][j] = MFMA_BF16(afh[i], bfh[j], acc[i][j], 0, 0, 0);
      if (t32 < 31) {
        asm volatile("s_waitcnt vmcnt(0)" ::: "memory");
        __builtin_amdgcn_s_barrier();
      }
    }
  }

#pragma unroll
  for (int i = 0; i < 4; ++i) {
#pragma unroll
    for (int j = 0; j < 4; ++j) {
      int col = n0 + wc * 64 + j * 16 + l16;
#pragma unroll
      for (int jj = 0; jj < 4; ++jj) {
        int row = m0 + wr * 64 + i * 16 + g * 4 + jj;
        int bb = row >> 9, l = row & 511;
        if (isq) {
          int hh = col >> 6, d = col & 63;
          qwsf[((bb * 16 + hh) * 512 + l) * 64 + d] = acc[i][j][jj];
        } else {
          int c2 = col - 1024;
          int hh = c2 >> 6, d = c2 & 63;
          vt[((bb * 16 + hh) * 64 + d) * 512 + l] = f2bf(acc[i][j][jj]);
        }
      }
    }
  }
}

// ---------------- fused relative attention (trig-GEMM band) ----------------
// Identical to round 7 except launch_bounds (256,2).
__global__ __launch_bounds__(256, 2) void k_attn(const unsigned short* __restrict__ xh,
                                                 const unsigned short* __restrict__ xl,
                                                 const float* __restrict__ qwsf,
                                                 const unsigned short* __restrict__ vt,
                                                 const unsigned short* __restrict__ poshi,
                                                 const unsigned short* __restrict__ poslo,
                                                 const float* __restrict__ posf,
                                                 const void* __restrict__ rrb,
                                                 const void* __restrict__ rwb,
                                                 const void* __restrict__ mask,
                                                 void* __restrict__ out) {
  __shared__ unsigned short Kh[64 * 64];
  __shared__ unsigned short Kl[64 * 64];
  __shared__ unsigned short Vv[64 * 64];
  __shared__ unsigned short Th[64 * 64];
  __shared__ unsigned short Tl[64 * 64];
  __shared__ unsigned short P[4][16][68];

  const bool isb = is_bf16_in(mask);
  const int qt = blockIdx.x;
  const int bh = blockIdx.y;
  const int b = bh >> 4, h = bh & 15;
  const int q0 = qt << 6;
  const int t = threadIdx.x;
  const int w = t >> 6;
  const int lane = t & 63;
  const int l16 = lane & 15;
  const int g = lane >> 4;
  const int bh64 = (b * 16 + h) * 64;

  const int srow = t >> 3;
  const int swz = ((t & 7) ^ (srow & 7)) << 3;

#pragma unroll
  for (int i = 0; i < 2; ++i) {
    int row = srow + i * 32;
    int scc = (t & 7) * 8;
    *(s8v*)&Kh[row * 64 + swz] = *(const s8v*)&xh[(b * 512 + row) * 1024 + h * 64 + scc];
    *(s8v*)&Kl[row * 64 + swz] = *(const s8v*)&xl[(b * 512 + row) * 1024 + h * 64 + scc];
    *(s8v*)&Vv[row * 64 + swz] = *(const s8v*)&vt[(bh64 + row) * 512 + scc];
    *(s8v*)&Th[row * 64 + swz] = *(const s8v*)&poshi[(512 + row) * 64 + scc];
    *(s8v*)&Tl[row * 64 + swz] = *(const s8v*)&poslo[(512 + row) * 64 + scc];
  }

  s8v qrh[2], qrl[2], qth[2], qtl[2];
  {
    const int qrow = q0 + (w << 4) + l16;
    const float* qb = &qwsf[((b * 16 + h) * 512 + qrow) * 64];
    float qw2[2][8];
#pragma unroll
    for (int f = 0; f < 2; ++f) {
      int d0 = f * 32 + g * 8;
#pragma unroll
      for (int j = 0; j < 8; ++j) {
        float qf = qb[d0 + j];
        float b1 = isb ? bf2f(((const unsigned short*)rrb)[h * 64 + d0 + j])
                       : ((const float*)rrb)[h * 64 + d0 + j];
        float b2 = isb ? bf2f(((const unsigned short*)rwb)[h * 64 + d0 + j])
                       : ((const float*)rwb)[h * 64 + d0 + j];
        float s1 = qf + b1;
        unsigned short h1 = f2bf(s1);
        qrh[f][j] = (short)h1;
        qrl[f][j] = (short)f2bf(s1 - bf2f(h1));
        qw2[f][j] = qf + b2;
      }
    }
#pragma unroll
    for (int j = 0; j < 8; ++j) {
      int jd = g * 8 + j;
      float s = posf[qrow * 64 + jd];
      float c = posf[qrow * 64 + 32 + jd];
      float qs = qw2[0][j], qc = qw2[1][j];
      float Qp = qs * c + qc * s;
      float Qpp = qc * c - qs * s;
      unsigned short h0 = f2bf(Qp);
      qth[0][j] = (short)h0;
      qtl[0][j] = (short)f2bf(Qp - bf2f(h0));
      unsigned short h1 = f2bf(Qpp);
      qth[1][j] = (short)h1;
      qtl[1][j] = (short)f2bf(Qpp - bf2f(h1));
    }
  }

  f4v accO[4];
#pragma unroll
  for (int d = 0; d < 4; ++d) accO[d] = (f4v){0.f, 0.f, 0.f, 0.f};
  float mrun[4] = {-3.0e38f, -3.0e38f, -3.0e38f, -3.0e38f};
  float lrun[4] = {0.f, 0.f, 0.f, 0.f};

  __syncthreads();

#pragma unroll 1
  for (int kt = 0; kt < 8; ++kt) {
    const int k0 = kt << 6;

    s8v nKh[2], nKl[2], nV[2], nTh[2], nTl[2];
    const bool hasNext = (kt < 7);
    if (hasNext) {
      const int k0n = k0 + 64;
      const int scc = (t & 7) * 8;
#pragma unroll
      for (int i = 0; i < 2; ++i) {
        int row = srow + i * 32;
        nKh[i] = *(const s8v*)&xh[(b * 512 + k0n + row) * 1024 + h * 64 + scc];
        nKl[i] = *(const s8v*)&xl[(b * 512 + k0n + row) * 1024 + h * 64 + scc];
        nV[i] = *(const s8v*)&vt[(bh64 + row) * 512 + k0n + scc];
        nTh[i] = *(const s8v*)&poshi[(512 + k0n + row) * 64 + scc];
        nTl[i] = *(const s8v*)&poslo[(512 + k0n + row) * 64 + scc];
      }
    }

    f4v acc[4];
#pragma unroll
    for (int ct = 0; ct < 4; ++ct) acc[ct] = (f4v){0.f, 0.f, 0.f, 0.f};
#pragma unroll
    for (int f = 0; f < 2; ++f) {
#pragma unroll
      for (int ct = 0; ct < 4; ++ct) {
        const int kr = ct * 16 + l16;
        const int eo = (((4 * f + g) ^ (l16 & 7)) << 3);
        s8v kh = *(const s8v*)&Kh[kr * 64 + eo];
        s8v klo = *(const s8v*)&Kl[kr * 64 + eo];
        s8v ph = *(const s8v*)&Th[kr * 64 + eo];
        s8v pl = *(const s8v*)&Tl[kr * 64 + eo];
        acc[ct] = MFMA_BF16(qrh[f], kh, acc[ct], 0, 0, 0);
        acc[ct] = MFMA_BF16(qrl[f], kh, acc[ct], 0, 0, 0);
        acc[ct] = MFMA_BF16(qrh[f], klo, acc[ct], 0, 0, 0);
        acc[ct] = MFMA_BF16(qth[f], ph, acc[ct], 0, 0, 0);
        acc[ct] = MFMA_BF16(qtl[f], ph, acc[ct], 0, 0, 0);
        acc[ct] = MFMA_BF16(qth[f], pl, acc[ct], 0, 0, 0);
      }
    }

    float sv[4][4];
#pragma unroll
    for (int ct = 0; ct < 4; ++ct) {
      int mi = b * 512 + k0 + ct * 16 + l16;
      float mv = isb ? bf2f(((const unsigned short*)mask)[mi]) : ((const float*)mask)[mi];
#pragma unroll
      for (int jj = 0; jj < 4; ++jj) {
        float s = acc[ct][jj] * mv;
        if (s == 0.f) s = -__builtin_inff();
        sv[ct][jj] = s;
      }
    }

    float sc[4];
#pragma unroll
    for (int jj = 0; jj < 4; ++jj) {
      float pm = fmaxf(fmaxf(sv[0][jj], sv[1][jj]), fmaxf(sv[2][jj], sv[3][jj]));
      pm = fmaxf(pm, __shfl_xor(pm, 1));
      pm = fmaxf(pm, __shfl_xor(pm, 2));
      pm = fmaxf(pm, __shfl_xor(pm, 4));
      pm = fmaxf(pm, __shfl_xor(pm, 8));
      float mnew = fmaxf(mrun[jj], pm);
      float scale = __expf(mrun[jj] - mnew);
      float ps = 0.f;
#pragma unroll
      for (int ct = 0; ct < 4; ++ct) {
        float p = __expf(sv[ct][jj] - mnew);
        unsigned short pb = f2bf(p);
        P[w][4 * g + jj][ct * 16 + l16] = pb;
        ps += bf2f(pb);
      }
      ps += __shfl_xor(ps, 1);
      ps += __shfl_xor(ps, 2);
      ps += __shfl_xor(ps, 4);
      ps += __shfl_xor(ps, 8);
      lrun[jj] = lrun[jj] * scale + ps;
      mrun[jj] = mnew;
      sc[jj] = scale;
    }

#pragma unroll
    for (int d = 0; d < 4; ++d)
#pragma unroll
      for (int jj = 0; jj < 4; ++jj) accO[d][jj] *= sc[jj];
#pragma unroll
    for (int ks = 0; ks < 2; ++ks) {
      s8v pf = *(const s8v*)&P[w][l16][ks * 32 + g * 8];
#pragma unroll
      for (int d = 0; d < 4; ++d) {
        const int vr = d * 16 + l16;
        const int eo = (((4 * ks + g) ^ (l16 & 7)) << 3);
        s8v vf = *(const s8v*)&Vv[vr * 64 + eo];
        accO[d] = MFMA_BF16(pf, vf, accO[d], 0, 0, 0);
      }
    }

    __syncthreads();
    if (hasNext) {
#pragma unroll
      for (int i = 0; i < 2; ++i) {
        int row = srow + i * 32;
        *(s8v*)&Kh[row * 64 + swz] = nKh[i];
        *(s8v*)&Kl[row * 64 + swz] = nKl[i];
        *(s8v*)&Vv[row * 64 + swz] = nV[i];
        *(s8v*)&Th[row * 64 + swz] = nTh[i];
        *(s8v*)&Tl[row * 64 + swz] = nTl[i];
      }
    }
    __syncthreads();
  }

  float inv[4];
#pragma unroll
  for (int jj = 0; jj < 4; ++jj) inv[jj] = 1.0f / lrun[jj];
#pragma unroll
  for (int d = 0; d < 4; ++d) {
#pragma unroll
    for (int jj = 0; jj < 4; ++jj) {
      int row = q0 + (w << 4) + 4 * g + jj;
      int idx = (b * 512 + row) * 1024 + h * 64 + d * 16 + l16;
      float val = accO[d][jj] * inv[jj];
      if (isb) ((unsigned short*)out)[idx] = f2bf(val);
      else ((float*)out)[idx] = val;
    }
  }
}

extern "C" void kernel_launch(void* const* d_in, const int* in_sizes, int n_in,
                              void* d_out, int out_size, void* d_ws, size_t ws_size,
                              hipStream_t stream) {
  (void)in_sizes; (void)n_in; (void)out_size; (void)ws_size;
  const void* x    = d_in[0];
  const void* mask = d_in[1];
  const void* wqv  = d_in[2];
  const void* rrb  = d_in[3];
  const void* rwb  = d_in[4];

  char* ws = (char*)d_ws;
  unsigned short* xh    = (unsigned short*)(ws);
  unsigned short* xl    = (unsigned short*)(ws + (8u << 20));
  unsigned short* Wh    = (unsigned short*)(ws + (16u << 20));
  unsigned short* Wl    = (unsigned short*)(ws + (20u << 20));
  float*          qwsf  = (float*)(ws + (24u << 20));
  unsigned short* vt    = (unsigned short*)(ws + (40u << 20));
  unsigned short* poshi = (unsigned short*)(ws + (48u << 20));
  unsigned short* poslo = (unsigned short*)(ws + (48u << 20) + (192u << 10));
  float*          posf  = (float*)(ws + (48u << 20) + (384u << 10));

  k_pos<<<dim3(272), 256, 0, stream>>>(poshi, poslo, posf);
  k_transpose<<<dim3(32, 16), 256, 0, stream>>>(wqv, mask, Wh, Wl);
  k_split_x<<<dim3(2048), 256, 0, stream>>>(x, mask, xh, xl);
  k_gemm<<<dim3(16, 32), 256, 0, stream>>>(xh, xl, Wh, Wl, qwsf, vt);
  k_attn<<<dim3(8, 128), 256, 0, stream>>>(xh, xl, qwsf, vt, poshi, poslo, posf, rrb, rwb, mask, (void*)d_out);
}